// Round 8
// baseline (305.780 us; speedup 1.0000x reference)
//
#include <hip/hip_runtime.h>
#include <hip/hip_bf16.h>

// LoRALinear with NF4 base: out = x @ W^T + (alpha/rank) * (x@A^T)@B^T
//  Fold: W_eff[o][i] = NF4[codes[o][i]] * scales[o][i/64] + 2 * sum_r B[o][r]*A[r][i]
//  One bf16 GEMM: out[M=8192][N=4096] = xb[M][K=4096] . W_eff[N][K]^T
//
// GEMM: 256x256 tile, BK=64, 8-phase schedule (R6 skeleton: reads interleaved
// into the MFMA cluster, E/O reg sets, 1 STG/phase, vmcnt(6)@odd), now using
// v_mfma_f32_32x32x16_bf16 (pipe ceiling 2495 vs 2176 TF; half the MFMA
// instruction count). Wave tile 128x64 = 4x2 C-tiles of 32x32 (16 f32 acc).
// A/B frag: row=lane&31, k=(lane>>5)*8+e. C/D: col=lane&31,
// row=(reg&3)+8*(reg>>2)+4*(lane>>5)  [m74/m101-verified].

#define IN_DIM  4096
#define OUT_DIM 4096
#define RANK    16
#define M_TOK   8192
#define LORA_SCALE 2.0f

typedef __bf16 bf16_t;
typedef bf16_t bf16x8  __attribute__((ext_vector_type(8)));
typedef float  f32x16  __attribute__((ext_vector_type(16)));

__device__ __constant__ float NF4_TAB[16] = {
    -1.0f, -0.6961928009986877f, -0.5250730514526367f, -0.39491748809814453f,
    -0.28444138169288635f, -0.18477343022823334f, -0.09105003625154495f, 0.0f,
    0.07958029955625534f, 0.16093020141124725f, 0.24611230194568634f,
    0.33791524171829224f, 0.44070982933044434f, 0.5626170039176941f,
    0.7229568362236328f, 1.0f};

// ------------------------------------------- prep W_eff + cast x (merged)
__global__ __launch_bounds__(256) void prep_all(
    const float* __restrict__ x,
    const int* __restrict__ codes, const float* __restrict__ scales,
    const float* __restrict__ la, const float* __restrict__ lb,
    bf16_t* __restrict__ W, bf16_t* __restrict__ xb)
{
    const int tid = threadIdx.x;
    if (blockIdx.x < 1024) {
        // ---- prep_w: 4 o-rows per block
        __shared__ float nf4s[16];
        __shared__ float lbs[4][16];
        const int o0 = blockIdx.x * 4;
        if (tid < 64) lbs[tid >> 4][tid & 15] = lb[(o0 + (tid >> 4)) * RANK + (tid & 15)] * LORA_SCALE;
        else if (tid < 80) nf4s[tid - 64] = NF4_TAB[tid - 64];
        __syncthreads();

        #pragma unroll
        for (int it = 0; it < 2; ++it) {
            const int i0 = (it * 256 + tid) * 8;
            float w[4][8];
            #pragma unroll
            for (int oo = 0; oo < 4; ++oo) {
                const size_t base = (size_t)(o0 + oo) * IN_DIM + i0;
                int4 c0 = *(const int4*)(codes + base);
                int4 c1 = *(const int4*)(codes + base + 4);
                const float sc = scales[(o0 + oo) * (IN_DIM / 64) + (i0 >> 6)];
                w[oo][0] = nf4s[c0.x] * sc; w[oo][1] = nf4s[c0.y] * sc;
                w[oo][2] = nf4s[c0.z] * sc; w[oo][3] = nf4s[c0.w] * sc;
                w[oo][4] = nf4s[c1.x] * sc; w[oo][5] = nf4s[c1.y] * sc;
                w[oo][6] = nf4s[c1.z] * sc; w[oo][7] = nf4s[c1.w] * sc;
            }
            #pragma unroll
            for (int r = 0; r < RANK; ++r) {
                float4 a0 = *(const float4*)(la + r * IN_DIM + i0);
                float4 a1 = *(const float4*)(la + r * IN_DIM + i0 + 4);
                #pragma unroll
                for (int oo = 0; oo < 4; ++oo) {
                    const float b = lbs[oo][r];
                    w[oo][0] += b * a0.x; w[oo][1] += b * a0.y;
                    w[oo][2] += b * a0.z; w[oo][3] += b * a0.w;
                    w[oo][4] += b * a1.x; w[oo][5] += b * a1.y;
                    w[oo][6] += b * a1.z; w[oo][7] += b * a1.w;
                }
            }
            #pragma unroll
            for (int oo = 0; oo < 4; ++oo) {
                bf16x8 v;
                #pragma unroll
                for (int j = 0; j < 8; ++j) v[j] = (bf16_t)w[oo][j];
                *(bf16x8*)(W + (size_t)(o0 + oo) * IN_DIM + i0) = v;
            }
        }
    } else {
        // ---- cast_x: 2048 blocks, grid-stride over 8192*4096/8 vec8 units
        const int bid = blockIdx.x - 1024;
        const int n8 = (M_TOK * IN_DIM) / 8;
        const int stride = 2048 * 256;
        for (int i = bid * 256 + tid; i < n8; i += stride) {
            const size_t e = (size_t)i * 8;
            float4 a = *(const float4*)(x + e);
            float4 b = *(const float4*)(x + e + 4);
            bf16x8 v;
            v[0] = (bf16_t)a.x; v[1] = (bf16_t)a.y; v[2] = (bf16_t)a.z; v[3] = (bf16_t)a.w;
            v[4] = (bf16_t)b.x; v[5] = (bf16_t)b.y; v[6] = (bf16_t)b.z; v[7] = (bf16_t)b.w;
            *(bf16x8*)(xb + e) = v;
        }
    }
}

// ---------------------------------------------------------------- GEMM
__global__ __launch_bounds__(512, 2) void gemm_bt(
    const bf16_t* __restrict__ A, const bf16_t* __restrict__ B,
    float* __restrict__ C)
{
    // [slot(2)][A|B][khalf(2)] 16KB regions = 128 KiB
    __shared__ __align__(128) char lds[131072];

    const int tid  = threadIdx.x;
    const int wave = tid >> 6;
    const int lane = tid & 63;

    const int flat = blockIdx.y * gridDim.x + blockIdx.x;     // 0..511
    const int swz  = (flat & 7) * 64 + (flat >> 3);           // XCD swizzle
    const int bx = swz & 15;
    const int by = swz >> 4;
    const int m0 = by * 256;
    const int n0 = bx * 256;

    const int wr = wave >> 2;         // 0..1
    const int wc = wave & 3;          // 0..3

    f32x16 acc[4][2];
    #pragma unroll
    for (int i = 0; i < 4; ++i)
        #pragma unroll
        for (int j = 0; j < 2; ++j) acc[i][j] = (f32x16)0.0f;

    const int l31  = lane & 31;
    const int hi   = lane >> 5;
    const int xorv = (l31 >> 1) & 3;               // R1-verified swizzle term
    const int cs0  = ((0 + hi) ^ xorv) << 4;       // kc=0 chunk byte
    const int cs1  = ((2 + hi) ^ xorv) << 4;       // kc=1 chunk byte
    const int base_a = (wr * 128 + l31) * 64;      // + (f>>1)*2048
    const int base_b = (wc * 64  + l31) * 64;      // + NH*2048

    // staging addressing: 2 x 16B per thread per 16KB region
    const int d0 = tid * 16, d1 = 8192 + tid * 16;
    const int sr0 = d0 >> 6, sr1 = d1 >> 6;
    const int sg0 = ((d0 >> 4) & 3) ^ ((sr0 >> 1) & 3);
    const int sg1 = ((d1 >> 4) & 3) ^ ((sr1 >> 1) & 3);
    const char* gA = (const char*)A;
    const char* gB = (const char*)B;

    bf16x8 fAe[8], fAo[8], fBe[2], fBo[2];

#define RD_A2(FA, SL, KH, J0) do {                                             \
    const char* b_ = lds + (SL) * 65536 + (KH) * 16384 + base_a               \
                     + ((J0) >> 1) * 2048;                                     \
    FA[(J0)]     = *(const bf16x8*)(b_ + cs0);                                 \
    FA[(J0) + 1] = *(const bf16x8*)(b_ + cs1);                                 \
} while (0)

#define RD_B(FB, SL, KH, NH) do {                                              \
    const char* b_ = lds + (SL) * 65536 + 32768 + (KH) * 16384 + base_b       \
                     + (NH) * 2048;                                            \
    FB[0] = *(const bf16x8*)(b_ + cs0);                                        \
    FB[1] = *(const bf16x8*)(b_ + cs1);                                        \
} while (0)

#define STG1(OPI, KH_, SL, T) do {                                             \
    const char* g_  = (OPI) ? gB : gA;                                         \
    const int   r0_ = (OPI) ? n0 : m0;                                         \
    const size_t ko_ = (size_t)(T) * 128 + (KH_) * 64;                         \
    const char* s0_ = g_ + (size_t)(r0_ + sr0) * 8192 + ko_ + (sg0 << 4);      \
    const char* s1_ = g_ + (size_t)(r0_ + sr1) * 8192 + ko_ + (sg1 << 4);      \
    char* db_ = lds + (SL) * 65536 + (OPI) * 32768 + (KH_) * 16384 + wave * 1024; \
    __builtin_amdgcn_global_load_lds(                                          \
        (const __attribute__((address_space(1))) void*)s0_,                    \
        (__attribute__((address_space(3))) void*)db_, 16, 0, 0);               \
    __builtin_amdgcn_global_load_lds(                                          \
        (const __attribute__((address_space(1))) void*)s1_,                    \
        (__attribute__((address_space(3))) void*)(db_ + 8192), 16, 0, 0);      \
} while (0)

#define MM2(FA, FB, I, NH) do {                                                \
    acc[I][NH] = __builtin_amdgcn_mfma_f32_32x32x16_bf16(                      \
        FA[2 * (I)], FB[0], acc[I][NH], 0, 0, 0);                              \
    acc[I][NH] = __builtin_amdgcn_mfma_f32_32x32x16_bf16(                      \
        FA[2 * (I) + 1], FB[1], acc[I][NH], 0, 0, 0);                          \
} while (0)

// phase: STG; [vmcnt(6)]; BAR; setprio1; 4x[2 MFMA || 2 reads]; setprio0; BAR
#define PHASE(SOP, SKH, SSL, ST, CHK, FA, FB, NH, RD1, RD2, RD3) do {          \
    STG1(SOP, SKH, SSL, ST);                                                   \
    if (CHK) { asm volatile("s_waitcnt vmcnt(6)" ::: "memory"); }              \
    __builtin_amdgcn_sched_barrier(0);                                         \
    __builtin_amdgcn_s_barrier();                                              \
    __builtin_amdgcn_s_setprio(1);                                             \
    MM2(FA, FB, 0, NH);                                                        \
    RD1;                                                                       \
    MM2(FA, FB, 1, NH);                                                        \
    RD2;                                                                       \
    MM2(FA, FB, 2, NH);                                                        \
    RD3;                                                                       \
    MM2(FA, FB, 3, NH);                                                        \
    __builtin_amdgcn_s_setprio(0);                                             \
    __builtin_amdgcn_s_barrier();                                              \
} while (0)

    // ---- prologue: stage S0 all (t0), then S1 A_k0,B_k0,A_k1 (t1)
    STG1(0, 0, 0, 0); STG1(1, 0, 0, 0); STG1(0, 1, 0, 0); STG1(1, 1, 0, 0);
    STG1(0, 0, 1, 1); STG1(1, 0, 1, 1); STG1(0, 1, 1, 1);
    asm volatile("s_waitcnt vmcnt(6)" ::: "memory");   // S0 fully landed
    __builtin_amdgcn_s_barrier();
    RD_A2(fAe, 0, 0, 0); RD_A2(fAe, 0, 0, 2);
    RD_A2(fAe, 0, 0, 4); RD_A2(fAe, 0, 0, 6);
    RD_B(fBe, 0, 0, 0);

    // ---- main loop: iter i computes K-tiles X=2i (slot0), Y=2i+1 (slot1)
    for (int i = 0; i < 32; ++i) {
        const int tY  = 2 * i + 1;
        const int tS0 = (2 * i + 2) & 63;
        const int tS1 = (2 * i + 3) & 63;
        // P0: MM X(k0,n0)
        PHASE(1, 1, 1, tY,  0, fAe, fBe, 0,
              RD_A2(fAo, 0, 1, 0), RD_A2(fAo, 0, 1, 2), RD_B(fBo, 0, 0, 1));
        // P1: MM X(k0,n1)
        PHASE(0, 0, 0, tS0, 1, fAe, fBo, 1,
              RD_A2(fAo, 0, 1, 4), RD_A2(fAo, 0, 1, 6), RD_B(fBe, 0, 1, 0));
        // P2: MM X(k1,n0)
        PHASE(1, 0, 0, tS0, 0, fAo, fBe, 0,
              RD_A2(fAe, 1, 0, 0), RD_A2(fAe, 1, 0, 2), RD_B(fBo, 0, 1, 1));
        // P3: MM X(k1,n1)
        PHASE(0, 1, 0, tS0, 1, fAo, fBo, 1,
              RD_A2(fAe, 1, 0, 4), RD_A2(fAe, 1, 0, 6), RD_B(fBe, 1, 0, 0));
        // P4: MM Y(k0,n0)
        PHASE(1, 1, 0, tS0, 0, fAe, fBe, 0,
              RD_A2(fAo, 1, 1, 0), RD_A2(fAo, 1, 1, 2), RD_B(fBo, 1, 0, 1));
        // P5: MM Y(k0,n1)
        PHASE(0, 0, 1, tS1, 1, fAe, fBo, 1,
              RD_A2(fAo, 1, 1, 4), RD_A2(fAo, 1, 1, 6), RD_B(fBe, 1, 1, 0));
        // P6: MM Y(k1,n0)
        PHASE(1, 0, 1, tS1, 0, fAo, fBe, 0,
              RD_A2(fAe, 0, 0, 0), RD_A2(fAe, 0, 0, 2), RD_B(fBo, 1, 1, 1));
        // P7: MM Y(k1,n1)
        PHASE(0, 1, 1, tS1, 1, fAo, fBo, 1,
              RD_A2(fAe, 0, 0, 4), RD_A2(fAe, 0, 0, 6), RD_B(fBe, 0, 0, 0));
    }

    // ---- C write: 32x32 D layout col=lane&31, row=(reg&3)+8*(reg>>2)+4*hi
    #pragma unroll
    for (int i = 0; i < 4; ++i) {
        #pragma unroll
        for (int j = 0; j < 2; ++j) {
            const int mb = m0 + wr * 128 + i * 32 + 4 * hi;
            const int nb = n0 + wc * 64 + j * 32 + l31;
            #pragma unroll
            for (int reg = 0; reg < 16; ++reg) {
                const int row = (reg & 3) + 8 * (reg >> 2);
                C[(size_t)(mb + row) * OUT_DIM + nb] = acc[i][j][reg];
            }
        }
    }
#undef RD_A2
#undef RD_B
#undef STG1
#undef MM2
#undef PHASE
}

// ---------------------------------------------------------------- launch
extern "C" void kernel_launch(void* const* d_in, const int* in_sizes, int n_in,
                              void* d_out, int out_size, void* d_ws, size_t ws_size,
                              hipStream_t stream) {
    const float* x      = (const float*)d_in[0];
    const int*   codes  = (const int*)d_in[1];
    const float* scales = (const float*)d_in[2];
    const float* la     = (const float*)d_in[3];
    const float* lb     = (const float*)d_in[4];
    float* out = (float*)d_out;

    bf16_t* W  = (bf16_t*)d_ws;
    bf16_t* xb = (bf16_t*)((char*)d_ws + (size_t)OUT_DIM * IN_DIM * 2);

    prep_all<<<1024 + 2048, 256, 0, stream>>>(x, codes, scales, la, lb, W, xb);

    dim3 grid(OUT_DIM / 256, M_TOK / 256);   // (16, 32) = 512 blocks
    gemm_bt<<<grid, 512, 0, stream>>>(xb, W, out);
}

// Round 9
// 288.864 us; speedup vs baseline: 1.0586x; 1.0586x over previous
//
#include <hip/hip_runtime.h>
#include <hip/hip_bf16.h>

// LoRALinear with NF4 base: out = x @ W^T + (alpha/rank) * (x@A^T)@B^T
//  Fold: W_eff[o][i] = NF4[codes[o][i]] * scales[o][i/64] + 2 * sum_r B[o][r]*A[r][i]
//  One bf16 GEMM: out[M=8192][N=4096] = xb[M][K=4096] . W_eff[N][K]^T
//
// GEMM: 256x256 tile, BK=64, 8-phase schedule, 16x16x32 MFMA (R6's verified
// 0-conflict layout), now SINGLE-BARRIER phases: the whole phase (16 MFMA ||
// 6 ds_read for next quads || 1 STG) is one cluster; phase ends with
// s_waitcnt lgkmcnt(0) [+ vmcnt(6) at odd phases] then ONE s_barrier.
// Safety audit: every region's old contents are consumed >=1 phase before its
// re-stage and the phase-end lgkm(0)+barrier drains all waves' reads before
// any wave's next-phase STG; vmcnt(6)@odd-end certifies each stage >=1
// barrier before its first read (all 8 phases audited, prologue included).

#define IN_DIM  4096
#define OUT_DIM 4096
#define RANK    16
#define M_TOK   8192
#define LORA_SCALE 2.0f

typedef __bf16 bf16_t;
typedef bf16_t bf16x8 __attribute__((ext_vector_type(8)));
typedef float  f32x4  __attribute__((ext_vector_type(4)));

__device__ __constant__ float NF4_TAB[16] = {
    -1.0f, -0.6961928009986877f, -0.5250730514526367f, -0.39491748809814453f,
    -0.28444138169288635f, -0.18477343022823334f, -0.09105003625154495f, 0.0f,
    0.07958029955625534f, 0.16093020141124725f, 0.24611230194568634f,
    0.33791524171829224f, 0.44070982933044434f, 0.5626170039176941f,
    0.7229568362236328f, 1.0f};

// ------------------------------------------- prep W_eff + cast x (merged)
__global__ __launch_bounds__(256) void prep_all(
    const float* __restrict__ x,
    const int* __restrict__ codes, const float* __restrict__ scales,
    const float* __restrict__ la, const float* __restrict__ lb,
    bf16_t* __restrict__ W, bf16_t* __restrict__ xb)
{
    const int tid = threadIdx.x;
    if (blockIdx.x < 1024) {
        __shared__ float nf4s[16];
        __shared__ float lbs[4][16];
        const int o0 = blockIdx.x * 4;
        if (tid < 64) lbs[tid >> 4][tid & 15] = lb[(o0 + (tid >> 4)) * RANK + (tid & 15)] * LORA_SCALE;
        else if (tid < 80) nf4s[tid - 64] = NF4_TAB[tid - 64];
        __syncthreads();

        #pragma unroll
        for (int it = 0; it < 2; ++it) {
            const int i0 = (it * 256 + tid) * 8;
            float w[4][8];
            #pragma unroll
            for (int oo = 0; oo < 4; ++oo) {
                const size_t base = (size_t)(o0 + oo) * IN_DIM + i0;
                int4 c0 = *(const int4*)(codes + base);
                int4 c1 = *(const int4*)(codes + base + 4);
                const float sc = scales[(o0 + oo) * (IN_DIM / 64) + (i0 >> 6)];
                w[oo][0] = nf4s[c0.x] * sc; w[oo][1] = nf4s[c0.y] * sc;
                w[oo][2] = nf4s[c0.z] * sc; w[oo][3] = nf4s[c0.w] * sc;
                w[oo][4] = nf4s[c1.x] * sc; w[oo][5] = nf4s[c1.y] * sc;
                w[oo][6] = nf4s[c1.z] * sc; w[oo][7] = nf4s[c1.w] * sc;
            }
            #pragma unroll
            for (int r = 0; r < RANK; ++r) {
                float4 a0 = *(const float4*)(la + r * IN_DIM + i0);
                float4 a1 = *(const float4*)(la + r * IN_DIM + i0 + 4);
                #pragma unroll
                for (int oo = 0; oo < 4; ++oo) {
                    const float b = lbs[oo][r];
                    w[oo][0] += b * a0.x; w[oo][1] += b * a0.y;
                    w[oo][2] += b * a0.z; w[oo][3] += b * a0.w;
                    w[oo][4] += b * a1.x; w[oo][5] += b * a1.y;
                    w[oo][6] += b * a1.z; w[oo][7] += b * a1.w;
                }
            }
            #pragma unroll
            for (int oo = 0; oo < 4; ++oo) {
                bf16x8 v;
                #pragma unroll
                for (int j = 0; j < 8; ++j) v[j] = (bf16_t)w[oo][j];
                *(bf16x8*)(W + (size_t)(o0 + oo) * IN_DIM + i0) = v;
            }
        }
    } else {
        const int bid = blockIdx.x - 1024;
        const int n8 = (M_TOK * IN_DIM) / 8;
        const int stride = 2048 * 256;
        for (int i = bid * 256 + tid; i < n8; i += stride) {
            const size_t e = (size_t)i * 8;
            float4 a = *(const float4*)(x + e);
            float4 b = *(const float4*)(x + e + 4);
            bf16x8 v;
            v[0] = (bf16_t)a.x; v[1] = (bf16_t)a.y; v[2] = (bf16_t)a.z; v[3] = (bf16_t)a.w;
            v[4] = (bf16_t)b.x; v[5] = (bf16_t)b.y; v[6] = (bf16_t)b.z; v[7] = (bf16_t)b.w;
            *(bf16x8*)(xb + e) = v;
        }
    }
}

// ---------------------------------------------------------------- GEMM
__global__ __launch_bounds__(512, 2) void gemm_bt(
    const bf16_t* __restrict__ A, const bf16_t* __restrict__ B,
    float* __restrict__ C)
{
    // [slot(2)][A|B][khalf(2)] 16KB regions = 128 KiB
    __shared__ __align__(128) char lds[131072];

    const int tid  = threadIdx.x;
    const int wave = tid >> 6;
    const int lane = tid & 63;

    const int flat = blockIdx.y * gridDim.x + blockIdx.x;     // 0..511
    const int swz  = (flat & 7) * 64 + (flat >> 3);           // XCD swizzle
    const int bx = swz & 15;
    const int by = swz >> 4;
    const int m0 = by * 256;
    const int n0 = bx * 256;

    const int wr = wave >> 2;         // 0..1
    const int wc = wave & 3;          // 0..3

    f32x4 acc[8][4];
    #pragma unroll
    for (int i = 0; i < 8; ++i)
        #pragma unroll
        for (int j = 0; j < 4; ++j) acc[i][j] = (f32x4)0.0f;

    const int frow = lane & 15;
    const int fch  = lane >> 4;
    const int fxor = (fch ^ ((frow >> 1) & 3)) << 4;   // R1-verified swizzle
    const int aoff = (wr * 128 + frow) * 64 + fxor;    // A frag f: +f*1024
    const int boff = (wc * 64  + frow) * 64 + fxor;    // B (nh,j): +nh*2048+j*1024

    // staging addressing: 2 x 16B per thread per 16KB region
    const int d0 = tid * 16, d1 = 8192 + tid * 16;
    const int sr0 = d0 >> 6, sr1 = d1 >> 6;
    const int sg0 = ((d0 >> 4) & 3) ^ ((sr0 >> 1) & 3);
    const int sg1 = ((d1 >> 4) & 3) ^ ((sr1 >> 1) & 3);
    const char* gA = (const char*)A;
    const char* gB = (const char*)B;

    bf16x8 fAe[8], fAo[8], fBe[2], fBo[2];

#define RD_A2(FA, SL, KH, J0) do {                                             \
    const char* b_ = lds + (SL) * 65536 + (KH) * 16384;                        \
    FA[(J0)]     = *(const bf16x8*)(b_ + aoff + (J0) * 1024);                  \
    FA[(J0) + 1] = *(const bf16x8*)(b_ + aoff + ((J0) + 1) * 1024);            \
} while (0)

#define RD_B(FB, SL, KH, NH) do {                                              \
    const char* b_ = lds + (SL) * 65536 + 32768 + (KH) * 16384;                \
    FB[0] = *(const bf16x8*)(b_ + boff + (NH) * 2048);                         \
    FB[1] = *(const bf16x8*)(b_ + boff + (NH) * 2048 + 1024);                  \
} while (0)

#define STG1(OPI, KH_, SL, T) do {                                             \
    const char* g_  = (OPI) ? gB : gA;                                         \
    const int   r0_ = (OPI) ? n0 : m0;                                         \
    const size_t ko_ = (size_t)(T) * 128 + (KH_) * 64;                         \
    const char* s0_ = g_ + (size_t)(r0_ + sr0) * 8192 + ko_ + (sg0 << 4);      \
    const char* s1_ = g_ + (size_t)(r0_ + sr1) * 8192 + ko_ + (sg1 << 4);      \
    char* db_ = lds + (SL) * 65536 + (OPI) * 32768 + (KH_) * 16384 + wave * 1024; \
    __builtin_amdgcn_global_load_lds(                                          \
        (const __attribute__((address_space(1))) void*)s0_,                    \
        (__attribute__((address_space(3))) void*)db_, 16, 0, 0);               \
    __builtin_amdgcn_global_load_lds(                                          \
        (const __attribute__((address_space(1))) void*)s1_,                    \
        (__attribute__((address_space(3))) void*)(db_ + 8192), 16, 0, 0);      \
} while (0)

#define MM4(FA, F0, FB, BI, NH) do {                                           \
    _Pragma("unroll")                                                          \
    for (int f_ = 0; f_ < 4; ++f_)                                             \
        acc[(F0) + f_][(NH) * 2 + (BI)] =                                      \
            __builtin_amdgcn_mfma_f32_16x16x32_bf16(                           \
                FA[(F0) + f_], FB[BI], acc[(F0) + f_][(NH) * 2 + (BI)], 0, 0, 0); \
} while (0)

// phase: one cluster {16 MFMA || 6 ds_read(next) || 1 STG}; end with
// lgkm(0) [+vmcnt(6) @odd] then ONE barrier.
#define PHASE(SOP, SKH, SSL, ST, CHK, FA, FB, NH, RD1, RD2, RD3) do {          \
    __builtin_amdgcn_sched_barrier(0);                                         \
    __builtin_amdgcn_s_setprio(1);                                             \
    MM4(FA, 0, FB, 0, NH);                                                     \
    RD1;                                                                       \
    MM4(FA, 0, FB, 1, NH);                                                     \
    STG1(SOP, SKH, SSL, ST);                                                   \
    MM4(FA, 4, FB, 0, NH);                                                     \
    RD2;                                                                       \
    MM4(FA, 4, FB, 1, NH);                                                     \
    RD3;                                                                       \
    __builtin_amdgcn_s_setprio(0);                                             \
    if (CHK) { asm volatile("s_waitcnt vmcnt(6) lgkmcnt(0)" ::: "memory"); }   \
    else     { asm volatile("s_waitcnt lgkmcnt(0)" ::: "memory"); }            \
    __builtin_amdgcn_sched_barrier(0);                                         \
    __builtin_amdgcn_s_barrier();                                              \
} while (0)

    // ---- prologue: stage S0 all (t0), then S1 A_k0,B_k0,A_k1 (t1)
    STG1(0, 0, 0, 0); STG1(1, 0, 0, 0); STG1(0, 1, 0, 0); STG1(1, 1, 0, 0);
    STG1(0, 0, 1, 1); STG1(1, 0, 1, 1); STG1(0, 1, 1, 1);
    asm volatile("s_waitcnt vmcnt(6)" ::: "memory");   // S0 fully landed
    __builtin_amdgcn_s_barrier();
    RD_A2(fAe, 0, 0, 0); RD_A2(fAe, 0, 0, 2);
    RD_A2(fAe, 0, 0, 4); RD_A2(fAe, 0, 0, 6);
    RD_B(fBe, 0, 0, 0);

    // ---- main loop: iter i computes K-tiles X=2i (slot0), Y=2i+1 (slot1)
    for (int i = 0; i < 32; ++i) {
        const int tY  = 2 * i + 1;
        const int tS0 = (2 * i + 2) & 63;
        const int tS1 = (2 * i + 3) & 63;
        // P0: MM X(k0,n0)
        PHASE(1, 1, 1, tY,  0, fAe, fBe, 0,
              RD_A2(fAo, 0, 1, 0), RD_A2(fAo, 0, 1, 2), RD_B(fBo, 0, 0, 1));
        // P1: MM X(k0,n1)
        PHASE(0, 0, 0, tS0, 1, fAe, fBo, 1,
              RD_A2(fAo, 0, 1, 4), RD_A2(fAo, 0, 1, 6), RD_B(fBe, 0, 1, 0));
        // P2: MM X(k1,n0)
        PHASE(1, 0, 0, tS0, 0, fAo, fBe, 0,
              RD_A2(fAe, 1, 0, 0), RD_A2(fAe, 1, 0, 2), RD_B(fBo, 0, 1, 1));
        // P3: MM X(k1,n1)
        PHASE(0, 1, 0, tS0, 1, fAo, fBo, 1,
              RD_A2(fAe, 1, 0, 4), RD_A2(fAe, 1, 0, 6), RD_B(fBe, 1, 0, 0));
        // P4: MM Y(k0,n0)
        PHASE(1, 1, 0, tS0, 0, fAe, fBe, 0,
              RD_A2(fAo, 1, 1, 0), RD_A2(fAo, 1, 1, 2), RD_B(fBo, 1, 0, 1));
        // P5: MM Y(k0,n1)
        PHASE(0, 0, 1, tS1, 1, fAe, fBo, 1,
              RD_A2(fAo, 1, 1, 4), RD_A2(fAo, 1, 1, 6), RD_B(fBe, 1, 1, 0));
        // P6: MM Y(k1,n0)
        PHASE(1, 0, 1, tS1, 0, fAo, fBe, 0,
              RD_A2(fAe, 0, 0, 0), RD_A2(fAe, 0, 0, 2), RD_B(fBo, 1, 1, 1));
        // P7: MM Y(k1,n1)
        PHASE(0, 1, 1, tS1, 1, fAo, fBo, 1,
              RD_A2(fAe, 0, 0, 4), RD_A2(fAe, 0, 0, 6), RD_B(fBe, 0, 0, 0));
    }

    // ---- C write: D layout col=lane&15, row=(lane>>4)*4+reg [m89-verified]
    const int crow = (lane >> 4) * 4;
    const int ccol = lane & 15;
    #pragma unroll
    for (int i = 0; i < 8; ++i) {
        #pragma unroll
        for (int j = 0; j < 4; ++j) {
            const int mb = m0 + wr * 128 + i * 16 + crow;
            const int nb = n0 + wc * 64 + j * 16 + ccol;
            #pragma unroll
            for (int r = 0; r < 4; ++r)
                C[(size_t)(mb + r) * OUT_DIM + nb] = acc[i][j][r];
        }
    }
#undef RD_A2
#undef RD_B
#undef STG1
#undef MM4
#undef PHASE
}

// ---------------------------------------------------------------- launch
extern "C" void kernel_launch(void* const* d_in, const int* in_sizes, int n_in,
                              void* d_out, int out_size, void* d_ws, size_t ws_size,
                              hipStream_t stream) {
    const float* x      = (const float*)d_in[0];
    const int*   codes  = (const int*)d_in[1];
    const float* scales = (const float*)d_in[2];
    const float* la     = (const float*)d_in[3];
    const float* lb     = (const float*)d_in[4];
    float* out = (float*)d_out;

    bf16_t* W  = (bf16_t*)d_ws;
    bf16_t* xb = (bf16_t*)((char*)d_ws + (size_t)OUT_DIM * IN_DIM * 2);

    prep_all<<<1024 + 2048, 256, 0, stream>>>(x, codes, scales, la, lb, W, xb);

    dim3 grid(OUT_DIM / 256, M_TOK / 256);   // (16, 32) = 512 blocks
    gemm_bt<<<grid, 512, 0, stream>>>(xb, W, out);
}

// Round 10
// 280.801 us; speedup vs baseline: 1.0890x; 1.0287x over previous
//
#include <hip/hip_runtime.h>
#include <hip/hip_bf16.h>

// LoRALinear with NF4 base: out = x @ W^T + (alpha/rank) * (x@A^T)@B^T
//  Fold: W_eff[o][i] = NF4[codes[o][i]] * scales[o][i/64] + 2 * sum_r B[o][r]*A[r][i]
//  One bf16 GEMM: out[M=8192][N=4096] = xb[M][K=4096] . W_eff[N][K]^T
//
// GEMM: 256x256 tile, BK=64, 8-phase schedule, 16x16x32 MFMA, single barrier
// per phase, NO explicit lgkm drain: every ds_read's consumer MFMA is in the
// next phase, so the compiler's counted lgkmcnt before that MFMA drains it
// before the next barrier (>=1 barrier before the region's re-stage).
// vmcnt(6) at odd-phase ends certifies stages (stage->first-read >= 5 phases,
// stage->cert <= 4 phases; audited load-by-load at steady state).

#define IN_DIM  4096
#define OUT_DIM 4096
#define RANK    16
#define M_TOK   8192
#define LORA_SCALE 2.0f

typedef __bf16 bf16_t;
typedef bf16_t bf16x8 __attribute__((ext_vector_type(8)));
typedef float  f32x4  __attribute__((ext_vector_type(4)));

__device__ __constant__ float NF4_TAB[16] = {
    -1.0f, -0.6961928009986877f, -0.5250730514526367f, -0.39491748809814453f,
    -0.28444138169288635f, -0.18477343022823334f, -0.09105003625154495f, 0.0f,
    0.07958029955625534f, 0.16093020141124725f, 0.24611230194568634f,
    0.33791524171829224f, 0.44070982933044434f, 0.5626170039176941f,
    0.7229568362236328f, 1.0f};

// ------------------------------------------- prep W_eff + cast x (merged)
__global__ __launch_bounds__(256) void prep_all(
    const float* __restrict__ x,
    const int* __restrict__ codes, const float* __restrict__ scales,
    const float* __restrict__ la, const float* __restrict__ lb,
    bf16_t* __restrict__ W, bf16_t* __restrict__ xb)
{
    const int tid = threadIdx.x;
    if (blockIdx.x < 1024) {
        __shared__ float nf4s[16];
        __shared__ float lbs[4][16];
        const int o0 = blockIdx.x * 4;
        if (tid < 64) lbs[tid >> 4][tid & 15] = lb[(o0 + (tid >> 4)) * RANK + (tid & 15)] * LORA_SCALE;
        else if (tid < 80) nf4s[tid - 64] = NF4_TAB[tid - 64];
        __syncthreads();

        #pragma unroll
        for (int it = 0; it < 2; ++it) {
            const int i0 = (it * 256 + tid) * 8;
            float w[4][8];
            #pragma unroll
            for (int oo = 0; oo < 4; ++oo) {
                const size_t base = (size_t)(o0 + oo) * IN_DIM + i0;
                int4 c0 = *(const int4*)(codes + base);
                int4 c1 = *(const int4*)(codes + base + 4);
                const float sc = scales[(o0 + oo) * (IN_DIM / 64) + (i0 >> 6)];
                w[oo][0] = nf4s[c0.x] * sc; w[oo][1] = nf4s[c0.y] * sc;
                w[oo][2] = nf4s[c0.z] * sc; w[oo][3] = nf4s[c0.w] * sc;
                w[oo][4] = nf4s[c1.x] * sc; w[oo][5] = nf4s[c1.y] * sc;
                w[oo][6] = nf4s[c1.z] * sc; w[oo][7] = nf4s[c1.w] * sc;
            }
            #pragma unroll
            for (int r = 0; r < RANK; ++r) {
                float4 a0 = *(const float4*)(la + r * IN_DIM + i0);
                float4 a1 = *(const float4*)(la + r * IN_DIM + i0 + 4);
                #pragma unroll
                for (int oo = 0; oo < 4; ++oo) {
                    const float b = lbs[oo][r];
                    w[oo][0] += b * a0.x; w[oo][1] += b * a0.y;
                    w[oo][2] += b * a0.z; w[oo][3] += b * a0.w;
                    w[oo][4] += b * a1.x; w[oo][5] += b * a1.y;
                    w[oo][6] += b * a1.z; w[oo][7] += b * a1.w;
                }
            }
            #pragma unroll
            for (int oo = 0; oo < 4; ++oo) {
                bf16x8 v;
                #pragma unroll
                for (int j = 0; j < 8; ++j) v[j] = (bf16_t)w[oo][j];
                *(bf16x8*)(W + (size_t)(o0 + oo) * IN_DIM + i0) = v;
            }
        }
    } else {
        const int bid = blockIdx.x - 1024;
        const int n8 = (M_TOK * IN_DIM) / 8;
        const int stride = 2048 * 256;
        for (int i = bid * 256 + tid; i < n8; i += stride) {
            const size_t e = (size_t)i * 8;
            float4 a = *(const float4*)(x + e);
            float4 b = *(const float4*)(x + e + 4);
            bf16x8 v;
            v[0] = (bf16_t)a.x; v[1] = (bf16_t)a.y; v[2] = (bf16_t)a.z; v[3] = (bf16_t)a.w;
            v[4] = (bf16_t)b.x; v[5] = (bf16_t)b.y; v[6] = (bf16_t)b.z; v[7] = (bf16_t)b.w;
            *(bf16x8*)(xb + e) = v;
        }
    }
}

// ---------------------------------------------------------------- GEMM
__global__ __launch_bounds__(512, 2) void gemm_bt(
    const bf16_t* __restrict__ A, const bf16_t* __restrict__ B,
    float* __restrict__ C)
{
    // [slot(2)][A|B][khalf(2)] 16KB regions = 128 KiB
    __shared__ __align__(128) char lds[131072];

    const int tid  = threadIdx.x;
    const int wave = tid >> 6;
    const int lane = tid & 63;

    const int flat = blockIdx.y * gridDim.x + blockIdx.x;     // 0..511
    const int swz  = (flat & 7) * 64 + (flat >> 3);           // XCD swizzle
    const int bx = swz & 15;
    const int by = swz >> 4;
    const int m0 = by * 256;
    const int n0 = bx * 256;

    const int wr = wave >> 2;         // 0..1
    const int wc = wave & 3;          // 0..3

    f32x4 acc[8][4];
    #pragma unroll
    for (int i = 0; i < 8; ++i)
        #pragma unroll
        for (int j = 0; j < 4; ++j) acc[i][j] = (f32x4)0.0f;

    const int frow = lane & 15;
    const int fch  = lane >> 4;
    const int fxor = (fch ^ ((frow >> 1) & 3)) << 4;   // R1-verified swizzle
    const int aoff = (wr * 128 + frow) * 64 + fxor;    // A frag f: +f*1024
    const int boff = (wc * 64  + frow) * 64 + fxor;    // B (nh,j): +nh*2048+j*1024

    // staging addressing: 2 x 16B per thread per 16KB region
    const int d0 = tid * 16, d1 = 8192 + tid * 16;
    const int sr0 = d0 >> 6, sr1 = d1 >> 6;
    const int sg0 = ((d0 >> 4) & 3) ^ ((sr0 >> 1) & 3);
    const int sg1 = ((d1 >> 4) & 3) ^ ((sr1 >> 1) & 3);
    const char* gA = (const char*)A;
    const char* gB = (const char*)B;

    bf16x8 fAe[8], fAo[8], fBe[2], fBo[2];

#define RD_A2(FA, SL, KH, J0) do {                                             \
    const char* b_ = lds + (SL) * 65536 + (KH) * 16384;                        \
    FA[(J0)]     = *(const bf16x8*)(b_ + aoff + (J0) * 1024);                  \
    FA[(J0) + 1] = *(const bf16x8*)(b_ + aoff + ((J0) + 1) * 1024);            \
} while (0)

#define RD_B(FB, SL, KH, NH) do {                                              \
    const char* b_ = lds + (SL) * 65536 + 32768 + (KH) * 16384;                \
    FB[0] = *(const bf16x8*)(b_ + boff + (NH) * 2048);                         \
    FB[1] = *(const bf16x8*)(b_ + boff + (NH) * 2048 + 1024);                  \
} while (0)

#define STG1(OPI, KH_, SL, T) do {                                             \
    const char* g_  = (OPI) ? gB : gA;                                         \
    const int   r0_ = (OPI) ? n0 : m0;                                         \
    const size_t ko_ = (size_t)(T) * 128 + (KH_) * 64;                         \
    const char* s0_ = g_ + (size_t)(r0_ + sr0) * 8192 + ko_ + (sg0 << 4);      \
    const char* s1_ = g_ + (size_t)(r0_ + sr1) * 8192 + ko_ + (sg1 << 4);      \
    char* db_ = lds + (SL) * 65536 + (OPI) * 32768 + (KH_) * 16384 + wave * 1024; \
    __builtin_amdgcn_global_load_lds(                                          \
        (const __attribute__((address_space(1))) void*)s0_,                    \
        (__attribute__((address_space(3))) void*)db_, 16, 0, 0);               \
    __builtin_amdgcn_global_load_lds(                                          \
        (const __attribute__((address_space(1))) void*)s1_,                    \
        (__attribute__((address_space(3))) void*)(db_ + 8192), 16, 0, 0);      \
} while (0)

#define MM4(FA, F0, FB, BI, NH) do {                                           \
    _Pragma("unroll")                                                          \
    for (int f_ = 0; f_ < 4; ++f_)                                             \
        acc[(F0) + f_][(NH) * 2 + (BI)] =                                      \
            __builtin_amdgcn_mfma_f32_16x16x32_bf16(                           \
                FA[(F0) + f_], FB[BI], acc[(F0) + f_][(NH) * 2 + (BI)], 0, 0, 0); \
} while (0)

// phase: one cluster {16 MFMA || 6 ds_read(next) || 1 STG}; NO lgkm drain
// (compiler inserts counted waits before next phase's consumer MFMAs);
// vmcnt(6) @odd-phase end certifies stages; ONE barrier per phase.
#define PHASE(SOP, SKH, SSL, ST, CHK, FA, FB, NH, RD1, RD2, RD3) do {          \
    __builtin_amdgcn_s_setprio(1);                                             \
    MM4(FA, 0, FB, 0, NH);                                                     \
    RD1;                                                                       \
    MM4(FA, 0, FB, 1, NH);                                                     \
    STG1(SOP, SKH, SSL, ST);                                                   \
    MM4(FA, 4, FB, 0, NH);                                                     \
    RD2;                                                                       \
    MM4(FA, 4, FB, 1, NH);                                                     \
    RD3;                                                                       \
    __builtin_amdgcn_s_setprio(0);                                             \
    if (CHK) { asm volatile("s_waitcnt vmcnt(6)" ::: "memory"); }              \
    __builtin_amdgcn_s_barrier();                                              \
} while (0)

    // ---- prologue: stage S0 all (t0), then S1 A_k0,B_k0,A_k1 (t1)
    STG1(0, 0, 0, 0); STG1(1, 0, 0, 0); STG1(0, 1, 0, 0); STG1(1, 1, 0, 0);
    STG1(0, 0, 1, 1); STG1(1, 0, 1, 1); STG1(0, 1, 1, 1);
    asm volatile("s_waitcnt vmcnt(6)" ::: "memory");   // S0 fully landed
    __builtin_amdgcn_s_barrier();
    RD_A2(fAe, 0, 0, 0); RD_A2(fAe, 0, 0, 2);
    RD_A2(fAe, 0, 0, 4); RD_A2(fAe, 0, 0, 6);
    RD_B(fBe, 0, 0, 0);

    // ---- main loop: iter i computes K-tiles X=2i (slot0), Y=2i+1 (slot1)
    for (int i = 0; i < 32; ++i) {
        const int tY  = 2 * i + 1;
        const int tS0 = (2 * i + 2) & 63;
        const int tS1 = (2 * i + 3) & 63;
        // P0: MM X(k0,n0)
        PHASE(1, 1, 1, tY,  0, fAe, fBe, 0,
              RD_A2(fAo, 0, 1, 0), RD_A2(fAo, 0, 1, 2), RD_B(fBo, 0, 0, 1));
        // P1: MM X(k0,n1)
        PHASE(0, 0, 0, tS0, 1, fAe, fBo, 1,
              RD_A2(fAo, 0, 1, 4), RD_A2(fAo, 0, 1, 6), RD_B(fBe, 0, 1, 0));
        // P2: MM X(k1,n0)
        PHASE(1, 0, 0, tS0, 0, fAo, fBe, 0,
              RD_A2(fAe, 1, 0, 0), RD_A2(fAe, 1, 0, 2), RD_B(fBo, 0, 1, 1));
        // P3: MM X(k1,n1)
        PHASE(0, 1, 0, tS0, 1, fAo, fBo, 1,
              RD_A2(fAe, 1, 0, 4), RD_A2(fAe, 1, 0, 6), RD_B(fBe, 1, 0, 0));
        // P4: MM Y(k0,n0)
        PHASE(1, 1, 0, tS0, 0, fAe, fBe, 0,
              RD_A2(fAo, 1, 1, 0), RD_A2(fAo, 1, 1, 2), RD_B(fBo, 1, 0, 1));
        // P5: MM Y(k0,n1)
        PHASE(0, 0, 1, tS1, 1, fAe, fBo, 1,
              RD_A2(fAo, 1, 1, 4), RD_A2(fAo, 1, 1, 6), RD_B(fBe, 1, 1, 0));
        // P6: MM Y(k1,n0)
        PHASE(1, 0, 1, tS1, 0, fAo, fBe, 0,
              RD_A2(fAe, 0, 0, 0), RD_A2(fAe, 0, 0, 2), RD_B(fBo, 1, 1, 1));
        // P7: MM Y(k1,n1)
        PHASE(0, 1, 1, tS1, 1, fAo, fBo, 1,
              RD_A2(fAe, 0, 0, 4), RD_A2(fAe, 0, 0, 6), RD_B(fBe, 0, 0, 0));
    }

    // ---- C write: D layout col=lane&15, row=(lane>>4)*4+reg [m89-verified]
    const int crow = (lane >> 4) * 4;
    const int ccol = lane & 15;
    #pragma unroll
    for (int i = 0; i < 8; ++i) {
        #pragma unroll
        for (int j = 0; j < 4; ++j) {
            const int mb = m0 + wr * 128 + i * 16 + crow;
            const int nb = n0 + wc * 64 + j * 16 + ccol;
            #pragma unroll
            for (int r = 0; r < 4; ++r)
                C[(size_t)(mb + r) * OUT_DIM + nb] = acc[i][j][r];
        }
    }
#undef RD_A2
#undef RD_B
#undef STG1
#undef MM4
#undef PHASE
}

// ---------------------------------------------------------------- launch
extern "C" void kernel_launch(void* const* d_in, const int* in_sizes, int n_in,
                              void* d_out, int out_size, void* d_ws, size_t ws_size,
                              hipStream_t stream) {
    const float* x      = (const float*)d_in[0];
    const int*   codes  = (const int*)d_in[1];
    const float* scales = (const float*)d_in[2];
    const float* la     = (const float*)d_in[3];
    const float* lb     = (const float*)d_in[4];
    float* out = (float*)d_out;

    bf16_t* W  = (bf16_t*)d_ws;
    bf16_t* xb = (bf16_t*)((char*)d_ws + (size_t)OUT_DIM * IN_DIM * 2);

    prep_all<<<1024 + 2048, 256, 0, stream>>>(x, codes, scales, la, lb, W, xb);

    dim3 grid(OUT_DIM / 256, M_TOK / 256);   // (16, 32) = 512 blocks
    gemm_bt<<<grid, 512, 0, stream>>>(xb, W, out);
}